// Round 1
// baseline (2850.767 us; speedup 1.0000x reference)
//
#include <hip/hip_runtime.h>
#include <hip/hip_bf16.h>

namespace {

constexpr int NV = 32000;
constexpr int NE = 256;
constexpr int NH = 512;
constexpr int NB = 32;
constexpr int NT = 64;
constexpr int NG = 3 * NH;    // 1536
constexpr int NM = NB * NT;   // 2048
constexpr int SOS = 1;

typedef __bf16 bf16_t;
typedef __bf16 bf16x8 __attribute__((ext_vector_type(8)));
typedef __bf16 bf16x4 __attribute__((ext_vector_type(4)));
typedef float f32x4 __attribute__((ext_vector_type(4)));

typedef __attribute__((address_space(1))) void gvoid_t;
typedef __attribute__((address_space(3))) void lvoid_t;

// ---------------- prologue kernels ----------------

// xT[t][e][b] = relu(embedding[token(b,t)][e])
__global__ __launch_bounds__(256) void k_embed(const int* __restrict__ tgt,
                                               const float* __restrict__ emb,
                                               float* __restrict__ xT) {
  int idx = blockIdx.x * 256 + threadIdx.x;   // = t*8192 + e*32 + b
  int b = idx & 31;
  int e = (idx >> 5) & 255;
  int t = idx >> 13;
  int tok = (t == 0) ? SOS : tgt[b * NT + (t - 1)];
  float v = emb[tok * NE + e];
  xT[idx] = v > 0.f ? v : 0.f;
}

// transpose encoder_hidden into h0T slot2 / h1T slot1 (the "t=-1" buffers)
__global__ __launch_bounds__(256) void k_hinit(const float* __restrict__ eh,
                                               float* __restrict__ h0T,
                                               float* __restrict__ h1T) {
  int idx = blockIdx.x * 256 + threadIdx.x;   // = l*16384 + b*512 + u
  int u = idx & 511;
  int b = (idx >> 9) & 31;
  int l = idx >> 14;
  float v = eh[idx];
  if (l == 0) h0T[2 * NH * NB + u * NB + b] = v;
  else        h1T[1 * NH * NB + u * NB + b] = v;
}

__global__ __launch_bounds__(256) void k_wcvt(const float* __restrict__ w,
                                              bf16_t* __restrict__ wb) {
  int idx = blockIdx.x * 256 + threadIdx.x;   // < NV*NH/4
  f32x4 v = ((const f32x4*)w)[idx];
  bf16x4 o;
  o[0] = (bf16_t)v[0]; o[1] = (bf16_t)v[1];
  o[2] = (bf16_t)v[2]; o[3] = (bf16_t)v[3];
  ((bf16x4*)wb)[idx] = o;
}

// Gi0T[t][j][b] = b_ih0[j] + sum_e xT[t][e][b] * W_ih0[j][e]
__global__ __launch_bounds__(256) void k_gi0(const float* __restrict__ xT,
                                             const float* __restrict__ Wih0,
                                             const float* __restrict__ bih0,
                                             float* __restrict__ Gi0T) {
  __shared__ float xs[NE * NB];   // 32 KB, [e][b]
  const int t = blockIdx.y;
  const float* xt = xT + t * (NE * NB);
  for (int i = threadIdx.x; i < NE * NB; i += 256) xs[i] = xt[i];
  __syncthreads();
  const int j = blockIdx.x * 8 + (threadIdx.x >> 5);
  const int b = threadIdx.x & 31;
  float acc = bih0[j];
  #pragma unroll 8
  for (int e = 0; e < NE; ++e) acc += xs[e * NB + b] * Wih0[j * NE + e];
  Gi0T[t * (NG * NB) + j * NB + b] = acc;
}

// ---------------- persistent recurrence ----------------

__global__ __launch_bounds__(256) void k_rnn(
    const float* __restrict__ Gi0T,
    const float* __restrict__ Whh0, const float* __restrict__ bhh0,
    const float* __restrict__ Wih1, const float* __restrict__ bih1,
    const float* __restrict__ Whh1, const float* __restrict__ bhh1,
    float* __restrict__ h0T, float* __restrict__ h1T,
    bf16_t* __restrict__ Abf, float* __restrict__ hfin,
    int* c0, int* c1) {
  const int tid = threadIdx.x;
  if (blockIdx.x < 64) {
    // ---- layer 0: 64 blocks, 8 units each, full K per thread ----
    const int b = tid & 31;
    const int u = blockIdx.x * 8 + (tid >> 5);
    const f32x4* wr = (const f32x4*)(Whh0 + (size_t)u * NH);
    const f32x4* wz = (const f32x4*)(Whh0 + (size_t)(NH + u) * NH);
    const f32x4* wn = (const f32x4*)(Whh0 + (size_t)(2 * NH + u) * NH);
    const float br = bhh0[u], bz = bhh0[NH + u], bn = bhh0[2 * NH + u];
    for (int t = 0; t < NT; ++t) {
      if (tid == 0) {
        if (t > 0)
          while (__hip_atomic_load(c0 + t - 1, __ATOMIC_ACQUIRE, __HIP_MEMORY_SCOPE_AGENT) < 64)
            __builtin_amdgcn_s_sleep(2);
        if (t >= 3)   // h0 slot reuse: layer1 of t-3 must be done reading
          while (__hip_atomic_load(c1 + t - 3, __ATOMIC_ACQUIRE, __HIP_MEMORY_SCOPE_AGENT) < 128)
            __builtin_amdgcn_s_sleep(2);
      }
      __syncthreads();
      const float* hin = h0T + ((t + 2) % 3) * (NH * NB);
      float hr = br, hz = bz, hn = bn;
      #pragma unroll 2
      for (int k4 = 0; k4 < NH / 4; ++k4) {
        const int k = 4 * k4;
        f32x4 w0 = wr[k4], w1 = wz[k4], w2 = wn[k4];
        float a0 = hin[(k + 0) * NB + b];
        float a1 = hin[(k + 1) * NB + b];
        float a2 = hin[(k + 2) * NB + b];
        float a3 = hin[(k + 3) * NB + b];
        hr += w0[0] * a0 + w0[1] * a1 + w0[2] * a2 + w0[3] * a3;
        hz += w1[0] * a0 + w1[1] * a1 + w1[2] * a2 + w1[3] * a3;
        hn += w2[0] * a0 + w2[1] * a1 + w2[2] * a2 + w2[3] * a3;
      }
      const float* gi = Gi0T + (size_t)t * (NG * NB);
      const float ir  = gi[u * NB + b];
      const float iz  = gi[(NH + u) * NB + b];
      const float in_ = gi[(2 * NH + u) * NB + b];
      const float r = 1.f / (1.f + __expf(-(ir + hr)));
      const float z = 1.f / (1.f + __expf(-(iz + hz)));
      const float n = tanhf(in_ + r * hn);
      const float hnew = (1.f - z) * n + z * hin[u * NB + b];
      h0T[(t % 3) * (NH * NB) + u * NB + b] = hnew;
      if (t == NT - 1) hfin[b * NH + u] = hnew;
      __syncthreads();
      if (tid == 0) {
        __threadfence();
        __hip_atomic_fetch_add(c0 + t, 1, __ATOMIC_RELEASE, __HIP_MEMORY_SCOPE_AGENT);
      }
    }
  } else {
    // ---- layer 1: 128 blocks, 4 units each, K split in halves ----
    const int half = tid >> 7;
    const int it = tid & 127;
    const int b = it & 31;
    const int u = (blockIdx.x - 64) * 4 + (it >> 5);
    const int ko = half * (NH / 2);
    __shared__ float part[128][8];
    const f32x4* xr  = (const f32x4*)(Wih1 + (size_t)u * NH + ko);
    const f32x4* xz  = (const f32x4*)(Wih1 + (size_t)(NH + u) * NH + ko);
    const f32x4* xn  = (const f32x4*)(Wih1 + (size_t)(2 * NH + u) * NH + ko);
    const f32x4* hrp = (const f32x4*)(Whh1 + (size_t)u * NH + ko);
    const f32x4* hzp = (const f32x4*)(Whh1 + (size_t)(NH + u) * NH + ko);
    const f32x4* hnp = (const f32x4*)(Whh1 + (size_t)(2 * NH + u) * NH + ko);
    for (int t = 0; t < NT; ++t) {
      if (tid == 0) {
        while (__hip_atomic_load(c0 + t, __ATOMIC_ACQUIRE, __HIP_MEMORY_SCOPE_AGENT) < 64)
          __builtin_amdgcn_s_sleep(2);
        if (t > 0)
          while (__hip_atomic_load(c1 + t - 1, __ATOMIC_ACQUIRE, __HIP_MEMORY_SCOPE_AGENT) < 128)
            __builtin_amdgcn_s_sleep(2);
      }
      __syncthreads();
      const float* xin = h0T + (t % 3) * (NH * NB);
      const float* hin = h1T + ((t + 1) & 1) * (NH * NB);
      float ir = 0.f, iz = 0.f, in_ = 0.f, hr = 0.f, hz = 0.f, hn = 0.f;
      #pragma unroll 2
      for (int k4 = 0; k4 < NH / 8; ++k4) {
        const int k = ko + 4 * k4;
        f32x4 u0 = xr[k4], u1 = xz[k4], u2 = xn[k4];
        f32x4 v0 = hrp[k4], v1 = hzp[k4], v2 = hnp[k4];
        float x0 = xin[(k + 0) * NB + b], x1 = xin[(k + 1) * NB + b];
        float x2 = xin[(k + 2) * NB + b], x3 = xin[(k + 3) * NB + b];
        float h0v = hin[(k + 0) * NB + b], h1v = hin[(k + 1) * NB + b];
        float h2v = hin[(k + 2) * NB + b], h3v = hin[(k + 3) * NB + b];
        ir  += u0[0] * x0 + u0[1] * x1 + u0[2] * x2 + u0[3] * x3;
        iz  += u1[0] * x0 + u1[1] * x1 + u1[2] * x2 + u1[3] * x3;
        in_ += u2[0] * x0 + u2[1] * x1 + u2[2] * x2 + u2[3] * x3;
        hr  += v0[0] * h0v + v0[1] * h1v + v0[2] * h2v + v0[3] * h3v;
        hz  += v1[0] * h0v + v1[1] * h1v + v1[2] * h2v + v1[3] * h3v;
        hn  += v2[0] * h0v + v2[1] * h1v + v2[2] * h2v + v2[3] * h3v;
      }
      if (half) {
        part[it][0] = ir; part[it][1] = iz; part[it][2] = in_;
        part[it][3] = hr; part[it][4] = hz; part[it][5] = hn;
      }
      __syncthreads();
      if (!half) {
        ir  += part[it][0] + bih1[u];
        iz  += part[it][1] + bih1[NH + u];
        in_ += part[it][2] + bih1[2 * NH + u];
        hr  += part[it][3] + bhh1[u];
        hz  += part[it][4] + bhh1[NH + u];
        hn  += part[it][5] + bhh1[2 * NH + u];
        const float r = 1.f / (1.f + __expf(-(ir + hr)));
        const float z = 1.f / (1.f + __expf(-(iz + hz)));
        const float n = tanhf(in_ + r * hn);
        const float hnew = (1.f - z) * n + z * hin[u * NB + b];
        h1T[(t & 1) * (NH * NB) + u * NB + b] = hnew;
        Abf[((size_t)b * NT + t) * NH + u] = (bf16_t)hnew;   // GEMM A row m=b*T+t
        if (t == NT - 1) hfin[NB * NH + b * NH + u] = hnew;
      }
      __syncthreads();
      if (tid == 0) {
        __threadfence();
        __hip_atomic_fetch_add(c1 + t, 1, __ATOMIC_RELEASE, __HIP_MEMORY_SCOPE_AGENT);
      }
    }
  }
}

// ---------------- output projection (bf16 MFMA, m97-style) ----------------

__global__ __launch_bounds__(256) void k_gemm(const bf16_t* __restrict__ A,
                                              const bf16_t* __restrict__ Bw,
                                              const float* __restrict__ bout,
                                              float* __restrict__ C) {
  __shared__ __align__(16) bf16_t As[2][128 * 32];
  __shared__ __align__(16) bf16_t Bs[2][128 * 32];
  const int n0 = blockIdx.x * 128;
  const int m0 = blockIdx.y * 128;
  const int tid = threadIdx.x;
  const int wave = tid >> 6;
  const int lane = tid & 63;
  const int r_in = lane >> 2;        // 16 rows per wave-instr
  const int c8 = (lane & 3) * 8;     // 16B chunk within 64B row

  const bf16_t* Ag = A  + (size_t)(m0 + wave * 32 + r_in) * NH + c8;
  const bf16_t* Bg = Bw + (size_t)(n0 + wave * 32 + r_in) * NH + c8;

  auto stage = [&](int buf, int kk) {
    bf16_t* la = &As[buf][(wave * 32) * 32];
    bf16_t* lb = &Bs[buf][(wave * 32) * 32];
    __builtin_amdgcn_global_load_lds((gvoid_t*)(Ag + kk),            (lvoid_t*)la,             16, 0, 0);
    __builtin_amdgcn_global_load_lds((gvoid_t*)(Ag + kk + 16 * NH),  (lvoid_t*)(la + 16 * 32), 16, 0, 0);
    __builtin_amdgcn_global_load_lds((gvoid_t*)(Bg + kk),            (lvoid_t*)lb,             16, 0, 0);
    __builtin_amdgcn_global_load_lds((gvoid_t*)(Bg + kk + 16 * NH),  (lvoid_t*)(lb + 16 * 32), 16, 0, 0);
  };

  f32x4 acc[4][4];
  #pragma unroll
  for (int i = 0; i < 4; ++i)
    #pragma unroll
    for (int j = 0; j < 4; ++j)
      acc[i][j] = (f32x4){0.f, 0.f, 0.f, 0.f};

  const int wm = (wave >> 1) * 64;
  const int wn = (wave & 1) * 64;
  const int arow = lane & 15;
  const int kg = (lane >> 4) * 8;

  stage(0, 0);
  __syncthreads();
  for (int kt = 0; kt < NH / 32; ++kt) {
    const int buf = kt & 1;
    if (kt + 1 < NH / 32) stage(buf ^ 1, (kt + 1) * 32);
    bf16x8 af[4], bfr[4];
    #pragma unroll
    for (int i = 0; i < 4; ++i) {
      af[i]  = *(const bf16x8*)&As[buf][(wm + i * 16 + arow) * 32 + kg];
      bfr[i] = *(const bf16x8*)&Bs[buf][(wn + i * 16 + arow) * 32 + kg];
    }
    #pragma unroll
    for (int i = 0; i < 4; ++i)
      #pragma unroll
      for (int j = 0; j < 4; ++j)
        acc[i][j] = __builtin_amdgcn_mfma_f32_16x16x32_bf16(af[i], bfr[j], acc[i][j], 0, 0, 0);
    __syncthreads();
  }

  const int crow = (lane >> 4) * 4;
  const int ccol = lane & 15;
  #pragma unroll
  for (int j = 0; j < 4; ++j) {
    const int gcol = n0 + wn + j * 16 + ccol;
    const float bb = bout[gcol];
    #pragma unroll
    for (int i = 0; i < 4; ++i) {
      const int grow = m0 + wm + i * 16 + crow;
      #pragma unroll
      for (int r = 0; r < 4; ++r)
        C[(size_t)(grow + r) * NV + gcol] = acc[i][j][r] + bb;
    }
  }
}

// ---------------- in-place row log_softmax ----------------

__global__ __launch_bounds__(256) void k_lsm(float* __restrict__ out) {
  __shared__ bf16_t row[NV];          // 64000 B stash (thread-private reuse)
  __shared__ float redm[4], reds[4];
  const int m = blockIdx.x;
  float* p = out + (size_t)m * NV;
  const int tid = threadIdx.x;
  float mx = -3.0e38f;
  for (int i = tid; i < NV; i += 256) {
    float x = p[i];
    row[i] = (bf16_t)x;
    mx = fmaxf(mx, x);
  }
  #pragma unroll
  for (int o = 1; o < 64; o <<= 1) mx = fmaxf(mx, __shfl_xor(mx, o, 64));
  if ((tid & 63) == 0) redm[tid >> 6] = mx;
  __syncthreads();
  mx = fmaxf(fmaxf(redm[0], redm[1]), fmaxf(redm[2], redm[3]));
  float s = 0.f;
  for (int i = tid; i < NV; i += 256) s += __expf((float)row[i] - mx);
  #pragma unroll
  for (int o = 1; o < 64; o <<= 1) s += __shfl_xor(s, o, 64);
  if ((tid & 63) == 0) reds[tid >> 6] = s;
  __syncthreads();
  const float lse = mx + __logf(reds[0] + reds[1] + reds[2] + reds[3]);
  for (int i = tid; i < NV; i += 256) p[i] = (float)row[i] - lse;
}

// ws layout (bytes)
constexpr size_t WS_C0  = 0;
constexpr size_t WS_C1  = 256;
constexpr size_t WS_XT  = 1024;
constexpr size_t WS_GI0 = WS_XT  + sizeof(float) * (size_t)NT * NE * NB;
constexpr size_t WS_H0  = WS_GI0 + sizeof(float) * (size_t)NT * NG * NB;
constexpr size_t WS_H1  = WS_H0  + sizeof(float) * 3 * NH * NB;
constexpr size_t WS_ABF = WS_H1  + sizeof(float) * 2 * NH * NB;
constexpr size_t WS_WB  = WS_ABF + sizeof(bf16_t) * (size_t)NM * NH;

}  // namespace

extern "C" void kernel_launch(void* const* d_in, const int* in_sizes, int n_in,
                              void* d_out, int out_size, void* d_ws, size_t ws_size,
                              hipStream_t stream) {
  const float* enc_h = (const float*)d_in[1];
  const int*   tgt   = (const int*)d_in[2];
  const float* emb   = (const float*)d_in[3];
  const float* Wih0  = (const float*)d_in[4];
  const float* Whh0  = (const float*)d_in[5];
  const float* bih0  = (const float*)d_in[6];
  const float* bhh0  = (const float*)d_in[7];
  const float* Wih1  = (const float*)d_in[8];
  const float* Whh1  = (const float*)d_in[9];
  const float* bih1  = (const float*)d_in[10];
  const float* bhh1  = (const float*)d_in[11];
  const float* Wout  = (const float*)d_in[12];
  const float* bout  = (const float*)d_in[13];

  char* ws = (char*)d_ws;
  int*    c0   = (int*)(ws + WS_C0);
  int*    c1   = (int*)(ws + WS_C1);
  float*  xT   = (float*)(ws + WS_XT);
  float*  Gi0T = (float*)(ws + WS_GI0);
  float*  h0T  = (float*)(ws + WS_H0);
  float*  h1T  = (float*)(ws + WS_H1);
  bf16_t* Abf  = (bf16_t*)(ws + WS_ABF);
  bf16_t* Wb   = (bf16_t*)(ws + WS_WB);

  float* out  = (float*)d_out;
  float* hfin = out + (size_t)NM * NV;

  hipMemsetAsync(ws, 0, 1024, stream);
  k_embed<<<(NT * NE * NB) / 256, 256, 0, stream>>>(tgt, emb, xT);
  k_hinit<<<(2 * NB * NH) / 256, 256, 0, stream>>>(enc_h, h0T, h1T);
  k_wcvt<<<(NV * NH / 4) / 256, 256, 0, stream>>>(Wout, Wb);
  k_gi0<<<dim3(NG / 8, NT), 256, 0, stream>>>(xT, Wih0, bih0, Gi0T);
  k_rnn<<<192, 256, 0, stream>>>(Gi0T, Whh0, bhh0, Wih1, bih1, Whh1, bhh1,
                                 h0T, h1T, Abf, hfin, c0, c1);
  k_gemm<<<dim3(NV / 128, NM / 128), 256, 0, stream>>>(Abf, Wb, bout, out);
  k_lsm<<<NM, 256, 0, stream>>>(out);
}

// Round 3
// 1070.179 us; speedup vs baseline: 2.6638x; 2.6638x over previous
//
#include <hip/hip_runtime.h>
#include <hip/hip_bf16.h>

namespace {

constexpr int NV = 32000;
constexpr int NE = 256;
constexpr int NH = 512;
constexpr int NB = 32;
constexpr int NT = 64;
constexpr int NG = 3 * NH;    // 1536
constexpr int NM = NB * NT;   // 2048
constexpr int SOS = 1;

typedef _Float16 f16_t;
typedef _Float16 f16x8 __attribute__((ext_vector_type(8)));
typedef _Float16 f16x2 __attribute__((ext_vector_type(2)));
typedef float f32x4 __attribute__((ext_vector_type(4)));

typedef __attribute__((address_space(1))) void gvoid_t;
typedef __attribute__((address_space(3))) void lvoid_t;

// fragment-order offset of h[u][b] inside a 512x32 f16 step buffer.
// B-frag of mfma_f32_16x16x32_f16: lane l holds col n=l&15, k=(l>>4)*8+j.
__device__ __forceinline__ int fragoff(int u, int b) {
  return ((b >> 4) * 16 + (u >> 5)) * 512 +
         ((((u >> 3) & 3) * 16) + (b & 15)) * 8 + (u & 7);
}

__device__ __forceinline__ void load_wf(const float* wrow, f16x8* wf) {
  #pragma unroll
  for (int kc = 0; kc < 16; ++kc) {
    f32x4 a = *(const f32x4*)(wrow + kc * 32);
    f32x4 c = *(const f32x4*)(wrow + kc * 32 + 4);
    f16x8 w;
    w[0] = (f16_t)a[0]; w[1] = (f16_t)a[1]; w[2] = (f16_t)a[2]; w[3] = (f16_t)a[3];
    w[4] = (f16_t)c[0]; w[5] = (f16_t)c[1]; w[6] = (f16_t)c[2]; w[7] = (f16_t)c[3];
    wf[kc] = w;
  }
}

__device__ __forceinline__ float sigm(float x) { return 1.f / (1.f + __expf(-x)); }

// ---------------- prologue kernels ----------------

// frag-order f16 initial hidden states
__global__ __launch_bounds__(256) void k_hinit(const float* __restrict__ eh,
                                               f16_t* __restrict__ hb0,
                                               f16_t* __restrict__ hb1) {
  int idx = blockIdx.x * 256 + threadIdx.x;   // l*16384 + b*512 + u
  int u = idx & 511;
  int b = (idx >> 9) & 31;
  int l = idx >> 14;
  f16_t v = (f16_t)eh[idx];
  (l ? hb1 : hb0)[fragoff(u, b)] = v;
}

__global__ __launch_bounds__(256) void k_wcvt(const float* __restrict__ w,
                                              f16_t* __restrict__ wb) {
  int idx = blockIdx.x * 256 + threadIdx.x;   // < NV*NH/4
  f32x4 v = ((const f32x4*)w)[idx];
  f16x2 o0, o1;
  o0[0] = (f16_t)v[0]; o0[1] = (f16_t)v[1];
  o1[0] = (f16_t)v[2]; o1[1] = (f16_t)v[3];
  ((f16x2*)wb)[2 * idx] = o0;
  ((f16x2*)wb)[2 * idx + 1] = o1;
}

// Gi0[t][j][b] = b_ih0[j] + sum_e relu(emb[tok(b,t)][e]) * W_ih0[j][e]  (f16 out)
__global__ __launch_bounds__(256) void k_gi0(const int* __restrict__ tgt,
                                             const float* __restrict__ emb,
                                             const float* __restrict__ Wih0,
                                             const float* __restrict__ bih0,
                                             f16_t* __restrict__ Gi0) {
  __shared__ float xs[NE * NB];   // [e][b]
  __shared__ int toks[NB];
  const int t = blockIdx.y;
  const int tid = threadIdx.x;
  if (tid < NB) toks[tid] = (t == 0) ? SOS : tgt[tid * NT + (t - 1)];
  __syncthreads();
  {
    const int b = tid >> 3, e0 = (tid & 7) * 32;
    const float* er = emb + (size_t)toks[b] * NE + e0;
    #pragma unroll 8
    for (int i = 0; i < 32; ++i) {
      float v = er[i];
      xs[(e0 + i) * NB + b] = v > 0.f ? v : 0.f;
    }
  }
  __syncthreads();
  const int j = blockIdx.x * 8 + (tid >> 5);
  const int b = tid & 31;
  float acc = bih0[j];
  const f32x4* wr = (const f32x4*)(Wih0 + (size_t)j * NE);
  #pragma unroll 4
  for (int e4 = 0; e4 < NE / 4; ++e4) {
    f32x4 w = wr[e4];
    acc += w[0] * xs[(4 * e4 + 0) * NB + b] + w[1] * xs[(4 * e4 + 1) * NB + b]
         + w[2] * xs[(4 * e4 + 2) * NB + b] + w[3] * xs[(4 * e4 + 3) * NB + b];
  }
  Gi0[((size_t)t * NG + j) * NB + b] = (f16_t)acc;
}

// ---------------- persistent MFMA recurrence ----------------
// blocks 0..7: layer 0 (64 units each).  blocks 8..23: layer 1 (32 units each).
// h passed via per-step frag-order f16 buffers hb0[t], hb1[t] (t=0 is initial).

__global__ __launch_bounds__(768) void k_rnn2(
    const f16_t* __restrict__ Gi0,
    const float* __restrict__ Whh0, const float* __restrict__ bhh0,
    const float* __restrict__ Wih1, const float* __restrict__ bih1,
    const float* __restrict__ Whh1, const float* __restrict__ bhh1,
    const float* __restrict__ eh,
    f16_t* __restrict__ hb0, f16_t* __restrict__ hb1,
    f16_t* __restrict__ Abf, float* __restrict__ hfin,
    int* c0, int* c1) {
  __shared__ __align__(16) float gLDS[6144];      // 24 KB
  __shared__ __align__(16) f16_t hstage[2048];    // 4 KB
  __shared__ __align__(16) f16_t astage[1024];    // 2 KB
  const int tid = threadIdx.x;
  const int wave = tid >> 6, lane = tid & 63;
  const int bid = blockIdx.x;
  const int eb = tid & 31, eu0 = (tid >> 5) & 15;

  if (bid < 8) {
    // ---------------- layer 0 ----------------
    const int ug = bid * 64;
    const int gate = wave >> 2, tile = wave & 3;
    const int row = gate * 512 + ug + tile * 16 + (lane & 15);
    f16x8 wf[16];
    load_wf(Whh0 + (size_t)row * NH + (lane >> 4) * 8, wf);

    float hprev[4], br[4], bz[4], bn[4];
    if (tid < 512) {
      #pragma unroll
      for (int i = 0; i < 4; ++i) {
        int u = ug + eu0 + i * 16;
        hprev[i] = eh[eb * NH + u];
        br[i] = bhh0[u]; bz[i] = bhh0[512 + u]; bn[i] = bhh0[1024 + u];
      }
    }

    for (int t = 0; t < NT; ++t) {
      float gr[4], gz[4], gn[4];
      if (tid < 512) {                       // prefetch gi (overlaps the wait)
        const f16_t* g = Gi0 + (size_t)t * NG * NB;
        #pragma unroll
        for (int i = 0; i < 4; ++i) {
          int u = ug + eu0 + i * 16;
          gr[i] = (float)g[u * NB + eb];
          gz[i] = (float)g[(512 + u) * NB + eb];
          gn[i] = (float)g[(1024 + u) * NB + eb];
        }
      }
      if (tid == 0 && t > 0) {
        while (__hip_atomic_load(c0 + t - 1, __ATOMIC_ACQUIRE, __HIP_MEMORY_SCOPE_AGENT) < 8)
          __builtin_amdgcn_s_sleep(2);
      }
      __syncthreads();
      const f16_t* hb = hb0 + (size_t)t * 16384;
      f32x4 acc0 = {0.f, 0.f, 0.f, 0.f}, acc1 = {0.f, 0.f, 0.f, 0.f};
      #pragma unroll
      for (int kc = 0; kc < 16; ++kc) {
        f16x8 b0 = *(const f16x8*)(hb + kc * 512 + lane * 8);
        f16x8 b1 = *(const f16x8*)(hb + (16 + kc) * 512 + lane * 8);
        acc0 = __builtin_amdgcn_mfma_f32_16x16x32_f16(wf[kc], b0, acc0, 0, 0, 0);
        acc1 = __builtin_amdgcn_mfma_f32_16x16x32_f16(wf[kc], b1, acc1, 0, 0, 0);
      }
      {
        const int m0 = (lane >> 4) * 4, col = lane & 15;
        #pragma unroll
        for (int r = 0; r < 4; ++r) {
          int ul = tile * 16 + m0 + r;
          gLDS[(gate * 64 + ul) * 32 + col] = acc0[r];
          gLDS[(gate * 64 + ul) * 32 + 16 + col] = acc1[r];
        }
      }
      __syncthreads();
      if (tid < 512) {
        #pragma unroll
        for (int i = 0; i < 4; ++i) {
          int ul = eu0 + i * 16;
          float rt = gLDS[(0 * 64 + ul) * 32 + eb];
          float zt = gLDS[(1 * 64 + ul) * 32 + eb];
          float nt_ = gLDS[(2 * 64 + ul) * 32 + eb];
          float r = sigm(gr[i] + rt + br[i]);
          float z = sigm(gz[i] + zt + bz[i]);
          float n = tanhf(gn[i] + r * (nt_ + bn[i]));
          float hnew = (1.f - z) * n + z * hprev[i];
          hprev[i] = hnew;
          hstage[((eb >> 4) * 2 + (ul >> 5)) * 512 +
                 ((((ul >> 3) & 3) * 16) + (eb & 15)) * 8 + (ul & 7)] = (f16_t)hnew;
          if (t == NT - 1) hfin[eb * NH + ug + ul] = hnew;
        }
      }
      __syncthreads();
      if (tid < 512) {
        const int chunk = tid >> 7, w = tid & 127;
        const uint2 v = *(const uint2*)(hstage + chunk * 512 + w * 4);
        *(uint2*)(hb0 + (size_t)(t + 1) * 16384 +
                  ((chunk >> 1) * 16 + (ug >> 5) + (chunk & 1)) * 512 + w * 4) = v;
      }
      __syncthreads();
      if (tid == 0) {
        __threadfence();
        __hip_atomic_fetch_add(c0 + t, 1, __ATOMIC_RELEASE, __HIP_MEMORY_SCOPE_AGENT);
      }
    }
  } else {
    // ---------------- layer 1 ----------------
    const int g = bid - 8, ug = g * 32;
    const int mm = wave >= 6;                 // 0: Wih1 (x=h0), 1: Whh1 (h1)
    const int w6 = mm ? wave - 6 : wave;
    const int gate = w6 >> 1, tile = w6 & 1;
    const int row = gate * 512 + ug + tile * 16 + (lane & 15);
    const float* W = mm ? Whh1 : Wih1;
    f16x8 wf[16];
    load_wf(W + (size_t)row * NH + (lane >> 4) * 8, wf);

    float hprev[2], bir[2], biz[2], bin_[2], bhr[2], bhz[2], bhn[2];
    if (tid < 512) {
      #pragma unroll
      for (int i = 0; i < 2; ++i) {
        int u = ug + eu0 + i * 16;
        hprev[i] = eh[16384 + eb * NH + u];
        bir[i] = bih1[u]; biz[i] = bih1[512 + u]; bin_[i] = bih1[1024 + u];
        bhr[i] = bhh1[u]; bhz[i] = bhh1[512 + u]; bhn[i] = bhh1[1024 + u];
      }
    }

    for (int t = 0; t < NT; ++t) {
      if (tid == 0) {
        while (__hip_atomic_load(c0 + t, __ATOMIC_ACQUIRE, __HIP_MEMORY_SCOPE_AGENT) < 8)
          __builtin_amdgcn_s_sleep(2);
        if (t > 0)
          while (__hip_atomic_load(c1 + t - 1, __ATOMIC_ACQUIRE, __HIP_MEMORY_SCOPE_AGENT) < 16)
            __builtin_amdgcn_s_sleep(2);
      }
      __syncthreads();
      const f16_t* hb = mm ? (hb1 + (size_t)t * 16384)
                           : (hb0 + (size_t)(t + 1) * 16384);
      f32x4 acc0 = {0.f, 0.f, 0.f, 0.f}, acc1 = {0.f, 0.f, 0.f, 0.f};
      #pragma unroll
      for (int kc = 0; kc < 16; ++kc) {
        f16x8 b0 = *(const f16x8*)(hb + kc * 512 + lane * 8);
        f16x8 b1 = *(const f16x8*)(hb + (16 + kc) * 512 + lane * 8);
        acc0 = __builtin_amdgcn_mfma_f32_16x16x32_f16(wf[kc], b0, acc0, 0, 0, 0);
        acc1 = __builtin_amdgcn_mfma_f32_16x16x32_f16(wf[kc], b1, acc1, 0, 0, 0);
      }
      {
        const int m0 = (lane >> 4) * 4, col = lane & 15;
        #pragma unroll
        for (int r = 0; r < 4; ++r) {
          int ul = tile * 16 + m0 + r;
          gLDS[((mm * 3 + gate) * 32 + ul) * 32 + col] = acc0[r];
          gLDS[((mm * 3 + gate) * 32 + ul) * 32 + 16 + col] = acc1[r];
        }
      }
      __syncthreads();
      if (tid < 512) {
        #pragma unroll
        for (int i = 0; i < 2; ++i) {
          int ul = eu0 + i * 16;
          float ir  = gLDS[((0 * 3 + 0) * 32 + ul) * 32 + eb] + bir[i];
          float iz  = gLDS[((0 * 3 + 1) * 32 + ul) * 32 + eb] + biz[i];
          float in_ = gLDS[((0 * 3 + 2) * 32 + ul) * 32 + eb] + bin_[i];
          float hr  = gLDS[((1 * 3 + 0) * 32 + ul) * 32 + eb] + bhr[i];
          float hz  = gLDS[((1 * 3 + 1) * 32 + ul) * 32 + eb] + bhz[i];
          float hn  = gLDS[((1 * 3 + 2) * 32 + ul) * 32 + eb] + bhn[i];
          float r = sigm(ir + hr);
          float z = sigm(iz + hz);
          float n = tanhf(in_ + r * hn);
          float hnew = (1.f - z) * n + z * hprev[i];
          hprev[i] = hnew;
          f16_t hv = (f16_t)hnew;
          hstage[(eb >> 4) * 512 +
                 ((((ul >> 3) & 3) * 16) + (eb & 15)) * 8 + (ul & 7)] = hv;
          astage[eb * 32 + ul] = hv;
          if (t == NT - 1) hfin[16384 + eb * NH + ug + ul] = hnew;
        }
      }
      __syncthreads();
      if (tid < 256) {
        const int chunk = tid >> 7, w = tid & 127;
        const uint2 v = *(const uint2*)(hstage + chunk * 512 + w * 4);
        *(uint2*)(hb1 + (size_t)(t + 1) * 16384 + (chunk * 16 + g) * 512 + w * 4) = v;
      } else if (tid < 512) {
        // FIX (R2 bug): cover ALL 32 batches — 256 threads x 4 f16.
        const int i2 = tid - 256;                 // 0..255
        const int b = i2 >> 3, uo = (i2 & 7) * 4; // b 0..31, uo 0..28
        *(uint2*)(Abf + ((size_t)(b * 64 + t)) * 512 + ug + uo) =
            *(const uint2*)(astage + b * 32 + uo);
      }
      __syncthreads();
      if (tid == 0) {
        __threadfence();
        __hip_atomic_fetch_add(c1 + t, 1, __ATOMIC_RELEASE, __HIP_MEMORY_SCOPE_AGENT);
      }
    }
  }
}

// ---------------- output projection (f16 MFMA, m97-style) ----------------

__global__ __launch_bounds__(256) void k_gemm(const f16_t* __restrict__ A,
                                              const f16_t* __restrict__ Bw,
                                              const float* __restrict__ bout,
                                              float* __restrict__ C) {
  __shared__ __align__(16) f16_t As[2][128 * 32];
  __shared__ __align__(16) f16_t Bs[2][128 * 32];
  const int n0 = blockIdx.x * 128;
  const int m0 = blockIdx.y * 128;
  const int tid = threadIdx.x;
  const int wave = tid >> 6;
  const int lane = tid & 63;
  const int r_in = lane >> 2;
  const int c8 = (lane & 3) * 8;

  const f16_t* Ag = A  + (size_t)(m0 + wave * 32 + r_in) * NH + c8;
  const f16_t* Bg = Bw + (size_t)(n0 + wave * 32 + r_in) * NH + c8;

  auto stage = [&](int buf, int kk) {
    f16_t* la = &As[buf][(wave * 32) * 32];
    f16_t* lb = &Bs[buf][(wave * 32) * 32];
    __builtin_amdgcn_global_load_lds((gvoid_t*)(Ag + kk),            (lvoid_t*)la,             16, 0, 0);
    __builtin_amdgcn_global_load_lds((gvoid_t*)(Ag + kk + 16 * NH),  (lvoid_t*)(la + 16 * 32), 16, 0, 0);
    __builtin_amdgcn_global_load_lds((gvoid_t*)(Bg + kk),            (lvoid_t*)lb,             16, 0, 0);
    __builtin_amdgcn_global_load_lds((gvoid_t*)(Bg + kk + 16 * NH),  (lvoid_t*)(lb + 16 * 32), 16, 0, 0);
  };

  f32x4 acc[4][4];
  #pragma unroll
  for (int i = 0; i < 4; ++i)
    #pragma unroll
    for (int j = 0; j < 4; ++j)
      acc[i][j] = (f32x4){0.f, 0.f, 0.f, 0.f};

  const int wm = (wave >> 1) * 64;
  const int wn = (wave & 1) * 64;
  const int arow = lane & 15;
  const int kg = (lane >> 4) * 8;

  stage(0, 0);
  __syncthreads();
  for (int kt = 0; kt < NH / 32; ++kt) {
    const int buf = kt & 1;
    if (kt + 1 < NH / 32) stage(buf ^ 1, (kt + 1) * 32);
    f16x8 af[4], bfr[4];
    #pragma unroll
    for (int i = 0; i < 4; ++i) {
      af[i]  = *(const f16x8*)&As[buf][(wm + i * 16 + arow) * 32 + kg];
      bfr[i] = *(const f16x8*)&Bs[buf][(wn + i * 16 + arow) * 32 + kg];
    }
    #pragma unroll
    for (int i = 0; i < 4; ++i)
      #pragma unroll
      for (int j = 0; j < 4; ++j)
        acc[i][j] = __builtin_amdgcn_mfma_f32_16x16x32_f16(af[i], bfr[j], acc[i][j], 0, 0, 0);
    __syncthreads();
  }

  const int crow = (lane >> 4) * 4;
  const int ccol = lane & 15;
  #pragma unroll
  for (int j = 0; j < 4; ++j) {
    const int gcol = n0 + wn + j * 16 + ccol;
    const float bb = bout[gcol];
    #pragma unroll
    for (int i = 0; i < 4; ++i) {
      const int grow = m0 + wm + i * 16 + crow;
      #pragma unroll
      for (int r = 0; r < 4; ++r)
        C[(size_t)(grow + r) * NV + gcol] = acc[i][j][r] + bb;
    }
  }
}

// ---------------- in-place row log_softmax ----------------

__global__ __launch_bounds__(256) void k_lsm(float* __restrict__ out) {
  __shared__ f16_t row[NV];
  __shared__ float redm[4], reds[4];
  const int m = blockIdx.x;
  float* p = out + (size_t)m * NV;
  const int tid = threadIdx.x;
  float mx = -3.0e38f;
  for (int i = tid; i < NV; i += 256) {
    float x = p[i];
    row[i] = (f16_t)x;
    mx = fmaxf(mx, x);
  }
  #pragma unroll
  for (int o = 1; o < 64; o <<= 1) mx = fmaxf(mx, __shfl_xor(mx, o, 64));
  if ((tid & 63) == 0) redm[tid >> 6] = mx;
  __syncthreads();
  mx = fmaxf(fmaxf(redm[0], redm[1]), fmaxf(redm[2], redm[3]));
  float s = 0.f;
  for (int i = tid; i < NV; i += 256) s += __expf((float)row[i] - mx);
  #pragma unroll
  for (int o = 1; o < 64; o <<= 1) s += __shfl_xor(s, o, 64);
  if ((tid & 63) == 0) reds[tid >> 6] = s;
  __syncthreads();
  const float lse = mx + __logf(reds[0] + reds[1] + reds[2] + reds[3]);
  for (int i = tid; i < NV; i += 256) p[i] = (float)row[i] - lse;
}

// ws layout (bytes)
constexpr size_t WS_C0  = 0;
constexpr size_t WS_C1  = 256;
constexpr size_t WS_GI0 = 1024;
constexpr size_t WS_HB0 = WS_GI0 + sizeof(f16_t) * (size_t)NT * NG * NB;       // 6.29 MB
constexpr size_t WS_HB1 = WS_HB0 + sizeof(f16_t) * (size_t)(NT + 1) * NH * NB; // +2.13 MB
constexpr size_t WS_ABF = WS_HB1 + sizeof(f16_t) * (size_t)(NT + 1) * NH * NB;
constexpr size_t WS_WF  = WS_ABF + sizeof(f16_t) * (size_t)NM * NH;

}  // namespace

extern "C" void kernel_launch(void* const* d_in, const int* in_sizes, int n_in,
                              void* d_out, int out_size, void* d_ws, size_t ws_size,
                              hipStream_t stream) {
  const float* enc_h = (const float*)d_in[1];
  const int*   tgt   = (const int*)d_in[2];
  const float* emb   = (const float*)d_in[3];
  const float* Wih0  = (const float*)d_in[4];
  const float* Whh0  = (const float*)d_in[5];
  const float* bih0  = (const float*)d_in[6];
  const float* bhh0  = (const float*)d_in[7];
  const float* Wih1  = (const float*)d_in[8];
  const float* Whh1  = (const float*)d_in[9];
  const float* bih1  = (const float*)d_in[10];
  const float* bhh1  = (const float*)d_in[11];
  const float* Wout  = (const float*)d_in[12];
  const float* bout  = (const float*)d_in[13];

  char* ws = (char*)d_ws;
  int*    c0   = (int*)(ws + WS_C0);
  int*    c1   = (int*)(ws + WS_C1);
  f16_t*  Gi0  = (f16_t*)(ws + WS_GI0);
  f16_t*  hb0  = (f16_t*)(ws + WS_HB0);
  f16_t*  hb1  = (f16_t*)(ws + WS_HB1);
  f16_t*  Abf  = (f16_t*)(ws + WS_ABF);
  f16_t*  Wf   = (f16_t*)(ws + WS_WF);

  float* out  = (float*)d_out;
  float* hfin = out + (size_t)NM * NV;

  hipMemsetAsync(ws, 0, 1024, stream);
  k_hinit<<<(2 * NB * NH) / 256, 256, 0, stream>>>(enc_h, hb0, hb1);
  k_gi0<<<dim3(NG / 8, NT), 256, 0, stream>>>(tgt, emb, Wih0, bih0, Gi0);
  k_rnn2<<<24, 768, 0, stream>>>(Gi0, Whh0, bhh0, Wih1, bih1, Whh1, bhh1,
                                 enc_h, hb0, hb1, Abf, hfin, c0, c1);
  k_wcvt<<<(NV * NH / 4) / 256, 256, 0, stream>>>(Wout, Wf);
  k_gemm<<<dim3(NV / 128, NM / 128), 256, 0, stream>>>(Abf, Wf, bout, out);
  k_lsm<<<NM, 256, 0, stream>>>(out);
}

// Round 4
// 1018.153 us; speedup vs baseline: 2.7999x; 1.0511x over previous
//
#include <hip/hip_runtime.h>
#include <hip/hip_bf16.h>

namespace {

constexpr int NV = 32000;
constexpr int NE = 256;
constexpr int NH = 512;
constexpr int NB = 32;
constexpr int NT = 64;
constexpr int NG = 3 * NH;    // 1536
constexpr int NM = NB * NT;   // 2048
constexpr int SOS = 1;

typedef _Float16 f16_t;
typedef _Float16 f16x8 __attribute__((ext_vector_type(8)));
typedef _Float16 f16x2 __attribute__((ext_vector_type(2)));
typedef float f32x4 __attribute__((ext_vector_type(4)));

typedef __attribute__((address_space(1))) void gvoid_t;
typedef __attribute__((address_space(3))) void lvoid_t;

// fragment-order offset of h[u][b] inside a 512x32 f16 step buffer.
// B-frag of mfma_f32_16x16x32_f16: lane l holds col n=l&15, k=(l>>4)*8+j.
__device__ __forceinline__ int fragoff(int u, int b) {
  return ((b >> 4) * 16 + (u >> 5)) * 512 +
         ((((u >> 3) & 3) * 16) + (b & 15)) * 8 + (u & 7);
}

__device__ __forceinline__ void load_wf(const float* wrow, f16x8* wf) {
  #pragma unroll
  for (int kc = 0; kc < 16; ++kc) {
    f32x4 a = *(const f32x4*)(wrow + kc * 32);
    f32x4 c = *(const f32x4*)(wrow + kc * 32 + 4);
    f16x8 w;
    w[0] = (f16_t)a[0]; w[1] = (f16_t)a[1]; w[2] = (f16_t)a[2]; w[3] = (f16_t)a[3];
    w[4] = (f16_t)c[0]; w[5] = (f16_t)c[1]; w[6] = (f16_t)c[2]; w[7] = (f16_t)c[3];
    wf[kc] = w;
  }
}

__device__ __forceinline__ float sigm(float x) { return 1.f / (1.f + __expf(-x)); }

// RELAXED agent-scope poll: sc1 load observes remote updates at the coherent
// point WITHOUT a per-iteration buffer_inv (the round-3 7.3us/step killer).
__device__ __forceinline__ void wait_ge(int* p, int target) {
  while (__hip_atomic_load(p, __ATOMIC_RELAXED, __HIP_MEMORY_SCOPE_AGENT) < target)
    __builtin_amdgcn_s_sleep(2);
}

// ---------------- prologue kernels ----------------

// frag-order f16 initial hidden states
__global__ __launch_bounds__(256) void k_hinit(const float* __restrict__ eh,
                                               f16_t* __restrict__ hb0,
                                               f16_t* __restrict__ hb1) {
  int idx = blockIdx.x * 256 + threadIdx.x;   // l*16384 + b*512 + u
  int u = idx & 511;
  int b = (idx >> 9) & 31;
  int l = idx >> 14;
  f16_t v = (f16_t)eh[idx];
  (l ? hb1 : hb0)[fragoff(u, b)] = v;
}

__global__ __launch_bounds__(256) void k_wcvt(const float* __restrict__ w,
                                              f16_t* __restrict__ wb) {
  int idx = blockIdx.x * 256 + threadIdx.x;   // < NV*NH/4
  f32x4 v = ((const f32x4*)w)[idx];
  f16x2 o0, o1;
  o0[0] = (f16_t)v[0]; o0[1] = (f16_t)v[1];
  o1[0] = (f16_t)v[2]; o1[1] = (f16_t)v[3];
  ((f16x2*)wb)[2 * idx] = o0;
  ((f16x2*)wb)[2 * idx + 1] = o1;
}

// Gi0[t][j][b] = b_ih0[j] + sum_e relu(emb[tok(b,t)][e]) * W_ih0[j][e]  (f16 out)
// grid (NG/64, NT): 8 j's per wave-group x 8 iterations — stages emb once per
// 64 rows instead of once per 8 (round-3 grid re-staged it 192x per t).
__global__ __launch_bounds__(256) void k_gi0(const int* __restrict__ tgt,
                                             const float* __restrict__ emb,
                                             const float* __restrict__ Wih0,
                                             const float* __restrict__ bih0,
                                             f16_t* __restrict__ Gi0) {
  __shared__ float xs[NE * NB];   // [e][b]
  __shared__ int toks[NB];
  const int t = blockIdx.y;
  const int tid = threadIdx.x;
  if (tid < NB) toks[tid] = (t == 0) ? SOS : tgt[tid * NT + (t - 1)];
  __syncthreads();
  {
    const int b = tid >> 3, e0 = (tid & 7) * 32;
    const float* er = emb + (size_t)toks[b] * NE + e0;
    #pragma unroll 8
    for (int i = 0; i < 32; ++i) {
      float v = er[i];
      xs[(e0 + i) * NB + b] = v > 0.f ? v : 0.f;
    }
  }
  __syncthreads();
  const int b = tid & 31;
  #pragma unroll
  for (int jj = 0; jj < 8; ++jj) {
    const int j = blockIdx.x * 64 + jj * 8 + (tid >> 5);
    float acc = bih0[j];
    const f32x4* wr = (const f32x4*)(Wih0 + (size_t)j * NE);
    #pragma unroll 4
    for (int e4 = 0; e4 < NE / 4; ++e4) {
      f32x4 w = wr[e4];
      acc += w[0] * xs[(4 * e4 + 0) * NB + b] + w[1] * xs[(4 * e4 + 1) * NB + b]
           + w[2] * xs[(4 * e4 + 2) * NB + b] + w[3] * xs[(4 * e4 + 3) * NB + b];
    }
    Gi0[((size_t)t * NG + j) * NB + b] = (f16_t)acc;
  }
}

// ---------------- persistent MFMA recurrence ----------------
// blocks 0..7: layer 0 (64 units each).  blocks 8..23: layer 1 (32 units each).
// h passed via per-step frag-order f16 buffers hb0[t], hb1[t] (t=0 is initial).
// Sync protocol (round-4): relaxed poll -> ONE acquire fence (buffer_inv) per
// step; __syncthreads (vmcnt drain) -> ONE release RMW (buffer_wbl2) per step.

__global__ __launch_bounds__(768) void k_rnn2(
    const f16_t* __restrict__ Gi0,
    const float* __restrict__ Whh0, const float* __restrict__ bhh0,
    const float* __restrict__ Wih1, const float* __restrict__ bih1,
    const float* __restrict__ Whh1, const float* __restrict__ bhh1,
    const float* __restrict__ eh,
    f16_t* __restrict__ hb0, f16_t* __restrict__ hb1,
    f16_t* __restrict__ Abf, float* __restrict__ hfin,
    int* c0, int* c1) {
  __shared__ __align__(16) float gLDS[6144];      // 24 KB
  __shared__ __align__(16) f16_t hstage[2048];    // 4 KB
  __shared__ __align__(16) f16_t astage[1024];    // 2 KB
  const int tid = threadIdx.x;
  const int wave = tid >> 6, lane = tid & 63;
  const int bid = blockIdx.x;
  const int eb = tid & 31, eu0 = (tid >> 5) & 15;

  if (bid < 8) {
    // ---------------- layer 0 ----------------
    const int ug = bid * 64;
    const int gate = wave >> 2, tile = wave & 3;
    const int row = gate * 512 + ug + tile * 16 + (lane & 15);
    f16x8 wf[16];
    load_wf(Whh0 + (size_t)row * NH + (lane >> 4) * 8, wf);

    float hprev[4], br[4], bz[4], bn[4];
    if (tid < 512) {
      #pragma unroll
      for (int i = 0; i < 4; ++i) {
        int u = ug + eu0 + i * 16;
        hprev[i] = eh[eb * NH + u];
        br[i] = bhh0[u]; bz[i] = bhh0[512 + u]; bn[i] = bhh0[1024 + u];
      }
    }

    for (int t = 0; t < NT; ++t) {
      float gr[4], gz[4], gn[4];
      if (tid < 512) {                       // prefetch gi (overlaps the wait)
        const f16_t* g = Gi0 + (size_t)t * NG * NB;
        #pragma unroll
        for (int i = 0; i < 4; ++i) {
          int u = ug + eu0 + i * 16;
          gr[i] = (float)g[u * NB + eb];
          gz[i] = (float)g[(512 + u) * NB + eb];
          gn[i] = (float)g[(1024 + u) * NB + eb];
        }
      }
      if (t > 0 && tid == 0) {
        wait_ge(c0 + t - 1, 8);
        __builtin_amdgcn_fence(__ATOMIC_ACQUIRE, "agent");
      }
      __syncthreads();
      const f16_t* hb = hb0 + (size_t)t * 16384;
      f32x4 acc0 = {0.f, 0.f, 0.f, 0.f}, acc1 = {0.f, 0.f, 0.f, 0.f};
      #pragma unroll
      for (int kc = 0; kc < 16; ++kc) {
        f16x8 b0 = *(const f16x8*)(hb + kc * 512 + lane * 8);
        f16x8 b1 = *(const f16x8*)(hb + (16 + kc) * 512 + lane * 8);
        acc0 = __builtin_amdgcn_mfma_f32_16x16x32_f16(wf[kc], b0, acc0, 0, 0, 0);
        acc1 = __builtin_amdgcn_mfma_f32_16x16x32_f16(wf[kc], b1, acc1, 0, 0, 0);
      }
      {
        const int m0 = (lane >> 4) * 4, col = lane & 15;
        #pragma unroll
        for (int r = 0; r < 4; ++r) {
          int ul = tile * 16 + m0 + r;
          gLDS[(gate * 64 + ul) * 32 + col] = acc0[r];
          gLDS[(gate * 64 + ul) * 32 + 16 + col] = acc1[r];
        }
      }
      __syncthreads();
      if (tid < 512) {
        #pragma unroll
        for (int i = 0; i < 4; ++i) {
          int ul = eu0 + i * 16;
          float rt = gLDS[(0 * 64 + ul) * 32 + eb];
          float zt = gLDS[(1 * 64 + ul) * 32 + eb];
          float nt_ = gLDS[(2 * 64 + ul) * 32 + eb];
          float r = sigm(gr[i] + rt + br[i]);
          float z = sigm(gz[i] + zt + bz[i]);
          float n = tanhf(gn[i] + r * (nt_ + bn[i]));
          float hnew = (1.f - z) * n + z * hprev[i];
          hprev[i] = hnew;
          hstage[((eb >> 4) * 2 + (ul >> 5)) * 512 +
                 ((((ul >> 3) & 3) * 16) + (eb & 15)) * 8 + (ul & 7)] = (f16_t)hnew;
          if (t == NT - 1) hfin[eb * NH + ug + ul] = hnew;
        }
      }
      __syncthreads();
      if (tid < 512) {
        const int chunk = tid >> 7, w = tid & 127;
        const uint2 v = *(const uint2*)(hstage + chunk * 512 + w * 4);
        *(uint2*)(hb0 + (size_t)(t + 1) * 16384 +
                  ((chunk >> 1) * 16 + (ug >> 5) + (chunk & 1)) * 512 + w * 4) = v;
      }
      __syncthreads();
      if (tid == 0)
        __hip_atomic_fetch_add(c0 + t, 1, __ATOMIC_RELEASE, __HIP_MEMORY_SCOPE_AGENT);
    }
  } else {
    // ---------------- layer 1 ----------------
    const int g = bid - 8, ug = g * 32;
    const int mm = wave >= 6;                 // 0: Wih1 (x=h0), 1: Whh1 (h1)
    const int w6 = mm ? wave - 6 : wave;
    const int gate = w6 >> 1, tile = w6 & 1;
    const int row = gate * 512 + ug + tile * 16 + (lane & 15);
    const float* W = mm ? Whh1 : Wih1;
    f16x8 wf[16];
    load_wf(W + (size_t)row * NH + (lane >> 4) * 8, wf);

    float hprev[2], bir[2], biz[2], bin_[2], bhr[2], bhz[2], bhn[2];
    if (tid < 512) {
      #pragma unroll
      for (int i = 0; i < 2; ++i) {
        int u = ug + eu0 + i * 16;
        hprev[i] = eh[16384 + eb * NH + u];
        bir[i] = bih1[u]; biz[i] = bih1[512 + u]; bin_[i] = bih1[1024 + u];
        bhr[i] = bhh1[u]; bhz[i] = bhh1[512 + u]; bhn[i] = bhh1[1024 + u];
      }
    }

    for (int t = 0; t < NT; ++t) {
      if (tid == 0) {
        wait_ge(c0 + t, 8);
        if (t > 0) wait_ge(c1 + t - 1, 16);
        __builtin_amdgcn_fence(__ATOMIC_ACQUIRE, "agent");
      }
      __syncthreads();
      const f16_t* hb = mm ? (hb1 + (size_t)t * 16384)
                           : (hb0 + (size_t)(t + 1) * 16384);
      f32x4 acc0 = {0.f, 0.f, 0.f, 0.f}, acc1 = {0.f, 0.f, 0.f, 0.f};
      #pragma unroll
      for (int kc = 0; kc < 16; ++kc) {
        f16x8 b0 = *(const f16x8*)(hb + kc * 512 + lane * 8);
        f16x8 b1 = *(const f16x8*)(hb + (16 + kc) * 512 + lane * 8);
        acc0 = __builtin_amdgcn_mfma_f32_16x16x32_f16(wf[kc], b0, acc0, 0, 0, 0);
        acc1 = __builtin_amdgcn_mfma_f32_16x16x32_f16(wf[kc], b1, acc1, 0, 0, 0);
      }
      {
        const int m0 = (lane >> 4) * 4, col = lane & 15;
        #pragma unroll
        for (int r = 0; r < 4; ++r) {
          int ul = tile * 16 + m0 + r;
          gLDS[((mm * 3 + gate) * 32 + ul) * 32 + col] = acc0[r];
          gLDS[((mm * 3 + gate) * 32 + ul) * 32 + 16 + col] = acc1[r];
        }
      }
      __syncthreads();
      if (tid < 512) {
        #pragma unroll
        for (int i = 0; i < 2; ++i) {
          int ul = eu0 + i * 16;
          float ir  = gLDS[((0 * 3 + 0) * 32 + ul) * 32 + eb] + bir[i];
          float iz  = gLDS[((0 * 3 + 1) * 32 + ul) * 32 + eb] + biz[i];
          float in_ = gLDS[((0 * 3 + 2) * 32 + ul) * 32 + eb] + bin_[i];
          float hr  = gLDS[((1 * 3 + 0) * 32 + ul) * 32 + eb] + bhr[i];
          float hz  = gLDS[((1 * 3 + 1) * 32 + ul) * 32 + eb] + bhz[i];
          float hn  = gLDS[((1 * 3 + 2) * 32 + ul) * 32 + eb] + bhn[i];
          float r = sigm(ir + hr);
          float z = sigm(iz + hz);
          float n = tanhf(in_ + r * hn);
          float hnew = (1.f - z) * n + z * hprev[i];
          hprev[i] = hnew;
          f16_t hv = (f16_t)hnew;
          hstage[(eb >> 4) * 512 +
                 ((((ul >> 3) & 3) * 16) + (eb & 15)) * 8 + (ul & 7)] = hv;
          astage[eb * 32 + ul] = hv;
          if (t == NT - 1) hfin[16384 + eb * NH + ug + ul] = hnew;
        }
      }
      __syncthreads();
      if (tid < 256) {
        const int chunk = tid >> 7, w = tid & 127;
        const uint2 v = *(const uint2*)(hstage + chunk * 512 + w * 4);
        *(uint2*)(hb1 + (size_t)(t + 1) * 16384 + (chunk * 16 + g) * 512 + w * 4) = v;
      } else if (tid < 512) {
        const int i2 = tid - 256;                 // 0..255
        const int b = i2 >> 3, uo = (i2 & 7) * 4; // b 0..31, uo 0..28
        *(uint2*)(Abf + ((size_t)(b * 64 + t)) * 512 + ug + uo) =
            *(const uint2*)(astage + b * 32 + uo);
      }
      __syncthreads();
      if (tid == 0)
        __hip_atomic_fetch_add(c1 + t, 1, __ATOMIC_RELEASE, __HIP_MEMORY_SCOPE_AGENT);
    }
  }
}

// ---------------- output projection (f16 MFMA, m97-style) ----------------

__global__ __launch_bounds__(256) void k_gemm(const f16_t* __restrict__ A,
                                              const f16_t* __restrict__ Bw,
                                              const float* __restrict__ bout,
                                              float* __restrict__ C) {
  __shared__ __align__(16) f16_t As[2][128 * 32];
  __shared__ __align__(16) f16_t Bs[2][128 * 32];
  const int n0 = blockIdx.x * 128;
  const int m0 = blockIdx.y * 128;
  const int tid = threadIdx.x;
  const int wave = tid >> 6;
  const int lane = tid & 63;
  const int r_in = lane >> 2;
  const int c8 = (lane & 3) * 8;

  const f16_t* Ag = A  + (size_t)(m0 + wave * 32 + r_in) * NH + c8;
  const f16_t* Bg = Bw + (size_t)(n0 + wave * 32 + r_in) * NH + c8;

  auto stage = [&](int buf, int kk) {
    f16_t* la = &As[buf][(wave * 32) * 32];
    f16_t* lb = &Bs[buf][(wave * 32) * 32];
    __builtin_amdgcn_global_load_lds((gvoid_t*)(Ag + kk),            (lvoid_t*)la,             16, 0, 0);
    __builtin_amdgcn_global_load_lds((gvoid_t*)(Ag + kk + 16 * NH),  (lvoid_t*)(la + 16 * 32), 16, 0, 0);
    __builtin_amdgcn_global_load_lds((gvoid_t*)(Bg + kk),            (lvoid_t*)lb,             16, 0, 0);
    __builtin_amdgcn_global_load_lds((gvoid_t*)(Bg + kk + 16 * NH),  (lvoid_t*)(lb + 16 * 32), 16, 0, 0);
  };

  f32x4 acc[4][4];
  #pragma unroll
  for (int i = 0; i < 4; ++i)
    #pragma unroll
    for (int j = 0; j < 4; ++j)
      acc[i][j] = (f32x4){0.f, 0.f, 0.f, 0.f};

  const int wm = (wave >> 1) * 64;
  const int wn = (wave & 1) * 64;
  const int arow = lane & 15;
  const int kg = (lane >> 4) * 8;

  stage(0, 0);
  __syncthreads();
  for (int kt = 0; kt < NH / 32; ++kt) {
    const int buf = kt & 1;
    if (kt + 1 < NH / 32) stage(buf ^ 1, (kt + 1) * 32);
    f16x8 af[4], bfr[4];
    #pragma unroll
    for (int i = 0; i < 4; ++i) {
      af[i]  = *(const f16x8*)&As[buf][(wm + i * 16 + arow) * 32 + kg];
      bfr[i] = *(const f16x8*)&Bs[buf][(wn + i * 16 + arow) * 32 + kg];
    }
    #pragma unroll
    for (int i = 0; i < 4; ++i)
      #pragma unroll
      for (int j = 0; j < 4; ++j)
        acc[i][j] = __builtin_amdgcn_mfma_f32_16x16x32_f16(af[i], bfr[j], acc[i][j], 0, 0, 0);
    __syncthreads();
  }

  const int crow = (lane >> 4) * 4;
  const int ccol = lane & 15;
  #pragma unroll
  for (int j = 0; j < 4; ++j) {
    const int gcol = n0 + wn + j * 16 + ccol;
    const float bb = bout[gcol];
    #pragma unroll
    for (int i = 0; i < 4; ++i) {
      const int grow = m0 + wm + i * 16 + crow;
      #pragma unroll
      for (int r = 0; r < 4; ++r)
        C[(size_t)(grow + r) * NV + gcol] = acc[i][j][r] + bb;
    }
  }
}

// ---------------- in-place row log_softmax ----------------

__global__ __launch_bounds__(256) void k_lsm(float* __restrict__ out) {
  __shared__ f16_t row[NV];
  __shared__ float redm[4], reds[4];
  const int m = blockIdx.x;
  float* p = out + (size_t)m * NV;
  const int tid = threadIdx.x;
  float mx = -3.0e38f;
  for (int i = tid; i < NV; i += 256) {
    float x = p[i];
    row[i] = (f16_t)x;
    mx = fmaxf(mx, x);
  }
  #pragma unroll
  for (int o = 1; o < 64; o <<= 1) mx = fmaxf(mx, __shfl_xor(mx, o, 64));
  if ((tid & 63) == 0) redm[tid >> 6] = mx;
  __syncthreads();
  mx = fmaxf(fmaxf(redm[0], redm[1]), fmaxf(redm[2], redm[3]));
  float s = 0.f;
  for (int i = tid; i < NV; i += 256) s += __expf((float)row[i] - mx);
  #pragma unroll
  for (int o = 1; o < 64; o <<= 1) s += __shfl_xor(s, o, 64);
  if ((tid & 63) == 0) reds[tid >> 6] = s;
  __syncthreads();
  const float lse = mx + __logf(reds[0] + reds[1] + reds[2] + reds[3]);
  for (int i = tid; i < NV; i += 256) p[i] = (float)row[i] - lse;
}

// ws layout (bytes)
constexpr size_t WS_C0  = 0;
constexpr size_t WS_C1  = 256;
constexpr size_t WS_GI0 = 1024;
constexpr size_t WS_HB0 = WS_GI0 + sizeof(f16_t) * (size_t)NT * NG * NB;       // 6.29 MB
constexpr size_t WS_HB1 = WS_HB0 + sizeof(f16_t) * (size_t)(NT + 1) * NH * NB; // +2.13 MB
constexpr size_t WS_ABF = WS_HB1 + sizeof(f16_t) * (size_t)(NT + 1) * NH * NB;
constexpr size_t WS_WF  = WS_ABF + sizeof(f16_t) * (size_t)NM * NH;

}  // namespace

extern "C" void kernel_launch(void* const* d_in, const int* in_sizes, int n_in,
                              void* d_out, int out_size, void* d_ws, size_t ws_size,
                              hipStream_t stream) {
  const float* enc_h = (const float*)d_in[1];
  const int*   tgt   = (const int*)d_in[2];
  const float* emb   = (const float*)d_in[3];
  const float* Wih0  = (const float*)d_in[4];
  const float* Whh0  = (const float*)d_in[5];
  const float* bih0  = (const float*)d_in[6];
  const float* bhh0  = (const float*)d_in[7];
  const float* Wih1  = (const float*)d_in[8];
  const float* Whh1  = (const float*)d_in[9];
  const float* bih1  = (const float*)d_in[10];
  const float* bhh1  = (const float*)d_in[11];
  const float* Wout  = (const float*)d_in[12];
  const float* bout  = (const float*)d_in[13];

  char* ws = (char*)d_ws;
  int*    c0   = (int*)(ws + WS_C0);
  int*    c1   = (int*)(ws + WS_C1);
  f16_t*  Gi0  = (f16_t*)(ws + WS_GI0);
  f16_t*  hb0  = (f16_t*)(ws + WS_HB0);
  f16_t*  hb1  = (f16_t*)(ws + WS_HB1);
  f16_t*  Abf  = (f16_t*)(ws + WS_ABF);
  f16_t*  Wf   = (f16_t*)(ws + WS_WF);

  float* out  = (float*)d_out;
  float* hfin = out + (size_t)NM * NV;

  hipMemsetAsync(ws, 0, 1024, stream);
  k_hinit<<<(2 * NB * NH) / 256, 256, 0, stream>>>(enc_h, hb0, hb1);
  k_gi0<<<dim3(NG / 64, NT), 256, 0, stream>>>(tgt, emb, Wih0, bih0, Gi0);
  k_rnn2<<<24, 768, 0, stream>>>(Gi0, Whh0, bhh0, Wih1, bih1, Whh1, bhh1,
                                 enc_h, hb0, hb1, Abf, hfin, c0, c1);
  k_wcvt<<<(NV * NH / 4) / 256, 256, 0, stream>>>(Wout, Wf);
  k_gemm<<<dim3(NV / 128, NM / 128), 256, 0, stream>>>(Abf, Wf, bout, out);
  k_lsm<<<NM, 256, 0, stream>>>(out);
}